// Round 7
// baseline (139.239 us; speedup 1.0000x reference)
//
#include <hip/hip_runtime.h>
#include <math.h>

// UpPolyAct: out = c0 + c1*x + 0.25*c2*( z_ee + V + W )
//   R = X M^T, L = M X, OO = L M^T
//   z_eo=(R+corr)^2, z_oe=(L+corr)^2, z_oo=OO^2, z_ee=(E X E)^2
//   U = z_oe + z_oo M,  V = M^T U,  W = z_eo M
// MFMA plan (32x32x16 bf16, 1 tile/wave, T-domain through U):
//   Rt = M X^T        A=tab(gr,rb)  B=Xr rows
//   Lt = X^T M^T      A=Xc rows     B=tab(gr,cb)
//   OOt = M Lt        A=tab(gr,rb)  B=Lr rows      (Lr = L row-major, T-write)
//   Ut = zoeT + M^T zooT   A=tab(g,rb)  B=Zoo rows (acc init = z_oeT regs)
//   W  = z_eo M       A=Zeo rows    B=tab(g,cb)    (untransposed)
//   V  = M^T U        A=tab(g,rb)   B=UtR rows     (untransposed)
//
// R7 = R6 resubmitted verbatim (R6 bench was an infra failure: "MI355X
// container failed twice" — kernel never compiled/ran on HW).
// R6 rationale: R5's VGPR=60 + MfmaUtil/VALUBusy both down proved the
// compiler SANK the global fragment loads into the MFMA phases (legal:
// g_ftw is read-only in-kernel), exposing ~200cyc L2 latency at each phase
// head. asm volatile("" : "+v"(frag)) makes the asm the definer: the load
// must complete by the pin and cannot be re-issued later.
//   fA/fB: issued at kernel start, pinned before B1 (P0 covers latency)
//   fU/fW: issued at top of P3 (Rt/Lt dead), pinned before B5 (P3 covers)

typedef short short8 __attribute__((ext_vector_type(8)));
typedef float f32x16 __attribute__((ext_vector_type(16)));

#define LSH 68  // bf16 LDS row stride (68 shorts = 136 B, rows 8B-aligned)

__device__ unsigned g_flag;                      // zero-initialized (.bss)
__device__ float g_gws[64];
__device__ __align__(16) short g_ftw[16 * 64 * 8];  // M fragments, slot=(t*2+blk)*4+kk

__device__ __forceinline__ short f2bf(float f) {
  unsigned u = __float_as_uint(f);
  u += 0x7FFFu + ((u >> 16) & 1u);
  return (short)(u >> 16);
}
__device__ __forceinline__ float bf2f(short s) {
  return __uint_as_float(((unsigned)(unsigned short)s) << 16);
}
__device__ __forceinline__ short8 ldrow(const short* p) {
  union { unsigned u[4]; short8 s; } v;
  const uint2 lo = *(const uint2*)p;
  const uint2 hi = *(const uint2*)(p + 4);
  v.u[0] = lo.x; v.u[1] = lo.y; v.u[2] = hi.x; v.u[3] = hi.y;
  return v.s;
}
__device__ __forceinline__ unsigned pk2(short a, short b) {
  return (unsigned)(unsigned short)a | ((unsigned)(unsigned short)b << 16);
}

// ---- setup: build g64 (64 f32) + ftab (16*64*8 bf16) into device globals ----
__global__ void uppolyact_setup() {
  if (g_flag == 0xC0FFEEu) return;  // replays early-out
  __shared__ float g64s[64];
  const int tid = threadIdx.x;
  if (tid < 64) {
    const int d = 2 * tid + 1;
    float s = 1.0f;
    for (int k = 1; k <= 32; ++k) {
      const int qq = (k * d) & 127;
      s += 2.0f * cosf((float)M_PI * (1.0f / 64.0f) * (float)qq);
    }
    const float gv = s * (1.0f / 64.0f);
    g64s[tid] = gv;
    g_gws[tid] = gv;
  }
  __syncthreads();
#pragma unroll
  for (int e = 0; e < 4; ++e) {
    const int entry = tid + 256 * e;  // 0..1023
    const int s_ = entry >> 6, ln = entry & 63;
    const int t_ = s_ >> 3, blk = (s_ >> 2) & 1, kk = s_ & 3;
    const int basei = kk * 16 + (ln >> 5) * 8 - (ln & 31) - 32 * blk;
    short* dst = &g_ftw[(s_ * 64 + ln) * 8];
#pragma unroll
    for (int j = 0; j < 8; ++j) {
      const int i0 = basei + j;
      const int idx = t_ ? ((-i0) & 63) : (i0 & 63);
      dst[j] = f2bf(g64s[idx]);
    }
  }
  __syncthreads();
  if (tid == 0) g_flag = 0xC0FFEEu;
}

__global__ __launch_bounds__(256, 4) void uppolyact_kernel(
    const float* __restrict__ x, const float* __restrict__ coef,
    float* __restrict__ out) {
  __shared__ __align__(16) short Xr[64 * LSH];    // X row-major bf16
  __shared__ __align__(16) short XcZ[64 * LSH];   // X^T row-major, then z_eo row-major
  __shared__ __align__(16) short LrU[64 * LSH];   // L row-major, then U^T row-major
  __shared__ __align__(16) short Zoo[64 * LSH];   // z_oo row-major
  __shared__ float g64[64];
  __shared__ float tvec[64], uvec[64], sRv[64], Luv[64];
  __shared__ float sigv;

  const int tid = threadIdx.x;
  const int lane = tid & 63;
  const int w = tid >> 6;
  const int q = lane >> 5;
  const int l31 = lane & 31;
  const int rb = w >> 1, cb = w & 1;
  const int jcol = cb * 32 + l31;  // this thread's fixed output column
  const size_t base = (size_t)blockIdx.x * 4096;
  const float* xb = x + base;
  const short8* ft8 = (const short8*)g_ftw;

  // ---- issue x loads FIRST (fragment order) ----
  float xcur[16];
#pragma unroll
  for (int r = 0; r < 16; ++r) {
    const int irow = rb * 32 + (r & 3) + 4 * q + 8 * (r >> 2);
    xcur[r] = xb[irow * 64 + jcol];
  }

  // ---- prefetch phase-C fragments from global (L2-hot, coalesced 1KB/wave)
  // fA = (gr,rb) slots (also reused by P3 OOt); fB = (gr,cb) slots
  short8 fA[4], fB[4];
#pragma unroll
  for (int kk = 0; kk < 4; ++kk) {
    fA[kk] = ft8[((2 + rb) * 4 + kk) * 64 + lane];
    fB[kk] = ft8[((2 + cb) * 4 + kk) * 64 + lane];
  }
  if (tid < 64) g64[tid] = g_gws[tid];

  // ---- P0: xcur regs -> Xr (scalar) + XcZ (packed b64) ----
#pragma unroll
  for (int k = 0; k < 4; ++k) {
    const int irowb = rb * 32 + 4 * q + 8 * k;  // irow = irowb + j, j=0..3
    short b[4];
#pragma unroll
    for (int j = 0; j < 4; ++j) {
      b[j] = f2bf(xcur[4 * k + j]);
      Xr[(irowb + j) * LSH + jcol] = b[j];
    }
    uint2 p;
    p.x = pk2(b[0], b[1]);
    p.y = pk2(b[2], b[3]);
    *(uint2*)&XcZ[jcol * LSH + irowb] = p;
  }
  // pin: force fA/fB to be materialized HERE (P0 covered the L2 latency);
  // the asm is now the defining access -> loads cannot sink into phase C
  // and cannot be re-issued at P3.
#pragma unroll
  for (int kk = 0; kk < 4; ++kk) {
    asm volatile("" : "+v"(fA[kk]), "+v"(fB[kk]));
  }
  __syncthreads();  // B1: g64 + Xr/XcZ published

  // ---- M1 tvec/uvec (all 256 threads, vectorized) ----
  {
    // tvec[j] = sum_i sign_i X[i][j] (rows of XcZ); uvec[i] = sum_j X[i][j] sign_j (rows of Xr)
    const int o = tid >> 1, h = tid & 1;  // o: output 0..127, h: half
    const short* src = (o < 64) ? &XcZ[o * LSH + 32 * h]
                                : &Xr[(o - 64) * LSH + 32 * h];
    float acc = 0.0f;
#pragma unroll
    for (int p = 0; p < 4; ++p) {
      const short8 v = ldrow(src + 8 * p);
#pragma unroll
      for (int j = 0; j < 8; ++j) {
        const float f = bf2f(v[j]);
        acc += (j & 1) ? -f : f;  // element index 32h+8p+j, parity = j&1
      }
    }
    acc += __shfl_xor(acc, 1);
    if (h == 0) {
      if (o < 64) tvec[o] = acc; else uvec[o - 64] = acc;
    }
  }
  __syncthreads();  // B2: tvec/uvec published

  // ---- Phase C: MFMA Rt, Lt (frags from regs) + M2 sRv/Luv + sigv ----
  f32x16 Rt, Lt;
#pragma unroll
  for (int r = 0; r < 16; ++r) { Rt[r] = 0.0f; Lt[r] = 0.0f; }
#pragma unroll
  for (int kk = 0; kk < 4; ++kk) {
    const short8 bR = ldrow(&Xr[(cb * 32 + l31) * LSH + kk * 16 + q * 8]);
    Rt = __builtin_amdgcn_mfma_f32_32x32x16_bf16(fA[kk], bR, Rt, 0, 0, 0);
    const short8 aL = ldrow(&XcZ[(rb * 32 + l31) * LSH + kk * 16 + q * 8]);
    Lt = __builtin_amdgcn_mfma_f32_32x32x16_bf16(aL, fB[kk], Lt, 0, 0, 0);
  }
  {
    // sRv[j] = sum_m tvec[m]*g64[(j-m)&63] ; Luv[i] = sum_m g64[(i-m)&63]*uvec[m]
    const int o = tid >> 1, h = tid & 1;
    const int o63 = o & 63;
    const float* vsrc = (o < 64) ? tvec : uvec;  // wave-uniform select
    float acc = 0.0f;
#pragma unroll
    for (int p = 0; p < 32; ++p) {
      const int m = 32 * h + p;
      acc += vsrc[m] * g64[(o63 - m) & 63];
    }
    acc += __shfl_xor(acc, 1);
    if (h == 0) {
      if (o < 64) sRv[o] = acc; else Luv[o - 64] = acc;
    }
  }
  if (w == 0) {  // sigv = s^T X s = sum_j sign_j * tvec[j]
    float sv = (lane & 1) ? -tvec[lane] : tvec[lane];
#pragma unroll
    for (int d_ = 1; d_ < 64; d_ <<= 1) sv += __shfl_xor(sv, d_);
    if (lane == 0) sigv = sv;
  }
  __syncthreads();  // B3

  // ---- P2: z_eoT -> XcZ (packed), Lt -> LrU (packed), z_oeT regs ----
  float zoe[16];
  {
    const int icol = cb * 32 + l31;
    const float sgi = (icol & 1) ? -1.0f : 1.0f;
#pragma unroll
    for (int k = 0; k < 4; ++k) {
      const int jb = rb * 32 + 4 * q + 8 * k;  // jrow = jb + t, t=0..3
      short ze[4], zl[4];
#pragma unroll
      for (int t = 0; t < 4; ++t) {
        const int r = 4 * k + t;
        const int jrow = jb + t;
        const float sgj = (jrow & 1) ? -1.0f : 1.0f;
        const float veo = Rt[r] + sgi * sRv[jrow] * (1.0f / 64.0f);
        ze[t] = f2bf(veo * veo);               // z_eo[i][j]
        zl[t] = f2bf(Lt[r]);                   // L[i][j]
        const float voe = Lt[r] + Luv[icol] * sgj * (1.0f / 64.0f);
        zoe[r] = voe * voe;                    // z_oeT[j][i] (C-layout)
      }
      uint2 pz, pl;
      pz.x = pk2(ze[0], ze[1]); pz.y = pk2(ze[2], ze[3]);
      pl.x = pk2(zl[0], zl[1]); pl.y = pk2(zl[2], zl[3]);
      *(uint2*)&XcZ[icol * LSH + jb] = pz;
      *(uint2*)&LrU[icol * LSH + jb] = pl;
    }
  }
  __syncthreads();  // B4

  // ---- P3: prefetch P4/P5 fragments (Rt/Lt now dead -> no VGPR peak);
  //      OOt = M*Lt ; z_oo -> Zoo (packed) ----
  short8 fU[4], fW[4];  // fU = (g,rb) (used P4 aU + P5 Vv-a); fW = (g,cb)
#pragma unroll
  for (int kk = 0; kk < 4; ++kk) {
    fU[kk] = ft8[((0 + rb) * 4 + kk) * 64 + lane];
    fW[kk] = ft8[((0 + cb) * 4 + kk) * 64 + lane];
  }
  f32x16 OOt;
#pragma unroll
  for (int r = 0; r < 16; ++r) OOt[r] = 0.0f;
#pragma unroll
  for (int kk = 0; kk < 4; ++kk) {
    const short8 b = ldrow(&LrU[(cb * 32 + l31) * LSH + kk * 16 + q * 8]);
    OOt = __builtin_amdgcn_mfma_f32_32x32x16_bf16(fA[kk], b, OOt, 0, 0, 0);
  }
  {
    const int icol = cb * 32 + l31;
#pragma unroll
    for (int k = 0; k < 4; ++k) {
      const int jb = rb * 32 + 4 * q + 8 * k;
      short zo[4];
#pragma unroll
      for (int t = 0; t < 4; ++t) {
        const int r = 4 * k + t;
        zo[t] = f2bf(OOt[r] * OOt[r]);
      }
      uint2 p;
      p.x = pk2(zo[0], zo[1]); p.y = pk2(zo[2], zo[3]);
      *(uint2*)&Zoo[icol * LSH + jb] = p;  // z_oo[i][j]
    }
  }
  // pin: fU/fW materialized here (P3 covered the latency); P4/P5 read regs.
#pragma unroll
  for (int kk = 0; kk < 4; ++kk) {
    asm volatile("" : "+v"(fU[kk]), "+v"(fW[kk]));
  }
  __syncthreads();  // B5

  // ---- P4: Ut = z_oeT + M^T z_ooT ; W = z_eo*M ; Ut -> LrU direct ----
  f32x16 Ut, Wv;
#pragma unroll
  for (int r = 0; r < 16; ++r) { Ut[r] = zoe[r]; Wv[r] = 0.0f; }
#pragma unroll
  for (int kk = 0; kk < 4; ++kk) {
    const short8 bU = ldrow(&Zoo[(cb * 32 + l31) * LSH + kk * 16 + q * 8]);
    Ut = __builtin_amdgcn_mfma_f32_32x32x16_bf16(fU[kk], bU, Ut, 0, 0, 0);
    const short8 aW = ldrow(&XcZ[(rb * 32 + l31) * LSH + kk * 16 + q * 8]);  // z_eo rows
    Wv = __builtin_amdgcn_mfma_f32_32x32x16_bf16(aW, fW[kk], Wv, 0, 0, 0);
  }
#pragma unroll
  for (int r = 0; r < 16; ++r) {
    const int jrow = rb * 32 + (r & 3) + 4 * q + 8 * (r >> 2);
    const int icol = cb * 32 + l31;
    LrU[jrow * LSH + icol] = f2bf(Ut[r]);  // U^T row-major (rows=j); strided, scalar
  }
  __syncthreads();  // B6

  // ---- P5: V = M^T U ; epilogue (x from regs; no global/Xr re-read) ----
  f32x16 Vv;
#pragma unroll
  for (int r = 0; r < 16; ++r) Vv[r] = 0.0f;
#pragma unroll
  for (int kk = 0; kk < 4; ++kk) {
    const short8 b = ldrow(&LrU[(cb * 32 + l31) * LSH + kk * 16 + q * 8]);
    Vv = __builtin_amdgcn_mfma_f32_32x32x16_bf16(fU[kk], b, Vv, 0, 0, 0);
  }

  const float c0 = coef[0], c1 = coef[1];
  const float c2q = 0.25f * coef[2];
  float* ob = out + base;
#pragma unroll
  for (int r = 0; r < 16; ++r) {
    const int irow = rb * 32 + (r & 3) + 4 * q + 8 * (r >> 2);
    const float sgi = (irow & 1) ? -1.0f : 1.0f;
    const float sgj = (jcol & 1) ? -1.0f : 1.0f;
    const float xv_ = bf2f(f2bf(xcur[r]));  // bit-identical to Xr round-trip
    const float vee = xv_ + (sgi * tvec[jcol] + uvec[irow] * sgj) * (1.0f / 64.0f) +
                      sgi * sgj * sigv * (1.0f / 4096.0f);
    const float zee = vee * vee;
    ob[irow * 64 + jcol] = c0 + c1 * xcur[r] + c2q * (zee + Vv[r] + Wv[r]);
  }
}

extern "C" void kernel_launch(void* const* d_in, const int* in_sizes, int n_in,
                              void* d_out, int out_size, void* d_ws,
                              size_t ws_size, hipStream_t stream) {
  const float* x = (const float*)d_in[0];
  const float* coef = (const float*)d_in[1];
  float* out = (float*)d_out;
  const int channels = out_size / 4096;  // 32*128 channels of 64x64
  uppolyact_setup<<<dim3(1), dim3(256), 0, stream>>>();
  uppolyact_kernel<<<dim3(channels), dim3(256), 0, stream>>>(x, coef, out);
}

// Round 10
// 127.747 us; speedup vs baseline: 1.0900x; 1.0900x over previous
//
#include <hip/hip_runtime.h>
#include <math.h>

// UpPolyAct: out = c0 + c1*x + 0.25*c2*( z_ee + V + W )
//   R = X M^T, L = M X, OO = L M^T
//   z_eo=(R+corr)^2, z_oe=(L+corr)^2, z_oo=OO^2, z_ee=(E X E)^2
//   U = z_oe + z_oo M,  V = M^T U,  W = z_eo M
// MFMA plan (32x32x16 bf16, 1 tile/wave, T-domain through U):
//   Rt = M X^T, Lt = X^T M^T, OOt = M Lt, Ut = zoeT + M^T zooT,
//   W = z_eo M, V = M^T U.
//
// R10 = R8 with ONE fix: the ftab staging registers are ext_vector_type(4)
// float (f32x4) instead of HIP float4. R9 compile error showed "+v" ties
// fail on struct float4 ("tied indirect register inputs") but work on
// ext_vector types (R7's short8 pins compiled+ran). R8 structure:
//  - R4's LDS-ftab fragment access (R5/R7 proved register fragments lose)
//  - 4 blocks/CU via LDS 52.7 -> ~35.6 KB:
//    * 3 tile buffers (z_eo->bufA, L->bufB, z_oo->bufC, U^T->bufB)
//    * 8 KB time-shared ftab: t=1 (gr) half through P3, swapped to t=0 (g)
//      half for P4/P5 (loads at P2-top, 8 VGPRs pinned before B5; +1 barrier)

typedef short short8 __attribute__((ext_vector_type(8)));
typedef float f32x16 __attribute__((ext_vector_type(16)));
typedef float f32x4 __attribute__((ext_vector_type(4)));

#define LSH 68  // bf16 LDS row stride (68 shorts = 136 B, rows 8B-aligned)

__device__ unsigned g_flag;                      // zero-initialized (.bss)
__device__ float g_gws[64];
__device__ __align__(16) short g_ftw[16 * 64 * 8];  // slot=(t*2+blk)*4+kk; t=0: [0,8KB), t=1: [8KB,16KB)

__device__ __forceinline__ short f2bf(float f) {
  unsigned u = __float_as_uint(f);
  u += 0x7FFFu + ((u >> 16) & 1u);
  return (short)(u >> 16);
}
__device__ __forceinline__ float bf2f(short s) {
  return __uint_as_float(((unsigned)(unsigned short)s) << 16);
}
__device__ __forceinline__ short8 ldrow(const short* p) {
  union { unsigned u[4]; short8 s; } v;
  const uint2 lo = *(const uint2*)p;
  const uint2 hi = *(const uint2*)(p + 4);
  v.u[0] = lo.x; v.u[1] = lo.y; v.u[2] = hi.x; v.u[3] = hi.y;
  return v.s;
}
__device__ __forceinline__ unsigned pk2(short a, short b) {
  return (unsigned)(unsigned short)a | ((unsigned)(unsigned short)b << 16);
}

// ---- setup: build g64 (64 f32) + ftab (16*64*8 bf16) into device globals ----
__global__ void uppolyact_setup() {
  if (g_flag == 0xC0FFEEu) return;  // replays early-out
  __shared__ float g64s[64];
  const int tid = threadIdx.x;
  if (tid < 64) {
    const int d = 2 * tid + 1;
    float s = 1.0f;
    for (int k = 1; k <= 32; ++k) {
      const int qq = (k * d) & 127;
      s += 2.0f * cosf((float)M_PI * (1.0f / 64.0f) * (float)qq);
    }
    const float gv = s * (1.0f / 64.0f);
    g64s[tid] = gv;
    g_gws[tid] = gv;
  }
  __syncthreads();
#pragma unroll
  for (int e = 0; e < 4; ++e) {
    const int entry = tid + 256 * e;  // 0..1023
    const int s_ = entry >> 6, ln = entry & 63;
    const int t_ = s_ >> 3, blk = (s_ >> 2) & 1, kk = s_ & 3;
    const int basei = kk * 16 + (ln >> 5) * 8 - (ln & 31) - 32 * blk;
    short* dst = &g_ftw[(s_ * 64 + ln) * 8];
#pragma unroll
    for (int j = 0; j < 8; ++j) {
      const int i0 = basei + j;
      const int idx = t_ ? ((-i0) & 63) : (i0 & 63);
      dst[j] = f2bf(g64s[idx]);
    }
  }
  __syncthreads();
  if (tid == 0) g_flag = 0xC0FFEEu;
}

__global__ __launch_bounds__(256, 4) void uppolyact_kernel(
    const float* __restrict__ x, const float* __restrict__ coef,
    float* __restrict__ out) {
  // bufA: X rows            -> z_eo rows (after B3)
  // bufB: X^T rows          -> L rows (after B3) -> U^T rows (after B5b)
  // bufC: z_oo rows (at P3)
  __shared__ __align__(16) short bufA[64 * LSH];
  __shared__ __align__(16) short bufB[64 * LSH];
  __shared__ __align__(16) short bufC[64 * LSH];
  __shared__ __align__(16) short ftab[8 * 64 * 8];  // time-shared: t=1 (gr) then t=0 (g); local slot = blk*4+kk
  __shared__ float g64[64];
  __shared__ float tvec[64], uvec[64], sRv[64], Luv[64];
  __shared__ float sigv;

  const int tid = threadIdx.x;
  const int lane = tid & 63;
  const int w = tid >> 6;
  const int q = lane >> 5;
  const int l31 = lane & 31;
  const int rb = w >> 1, cb = w & 1;
  const int jcol = cb * 32 + l31;  // this thread's fixed output column
  const size_t base = (size_t)blockIdx.x * 4096;
  const float* xb = x + base;

  // ---- issue x loads FIRST (fragment order) ----
  float xcur[16];
#pragma unroll
  for (int r = 0; r < 16; ++r) {
    const int irow = rb * 32 + (r & 3) + 4 * q + 8 * (r >> 2);
    xcur[r] = xb[irow * 64 + jcol];
  }
  // ---- issue ftab t=1 (gr) copy loads: 8 KB, L2/L3-hot across all blocks
  f32x4 t0, t1;
  {
    const f32x4* fsrc = (const f32x4*)(g_ftw + 8 * 64 * 8);  // t=1 half
    t0 = fsrc[tid];
    t1 = fsrc[tid + 256];
  }
  if (tid < 64) g64[tid] = g_gws[tid];

  // ---- P0: xcur regs -> bufA (X rows, scalar) + bufB (X^T, packed b64) ----
#pragma unroll
  for (int k = 0; k < 4; ++k) {
    const int irowb = rb * 32 + 4 * q + 8 * k;  // irow = irowb + j, j=0..3
    short b[4];
#pragma unroll
    for (int j = 0; j < 4; ++j) {
      b[j] = f2bf(xcur[4 * k + j]);
      bufA[(irowb + j) * LSH + jcol] = b[j];
    }
    uint2 p;
    p.x = pk2(b[0], b[1]);
    p.y = pk2(b[2], b[3]);
    *(uint2*)&bufB[jcol * LSH + irowb] = p;
  }
  {
    f32x4* fdst = (f32x4*)ftab;
    fdst[tid] = t0;
    fdst[tid + 256] = t1;
  }
  __syncthreads();  // B1: g64 + bufA/bufB + ftab(t=1) published

  // ---- M1 tvec/uvec (all 256 threads, vectorized) ----
  {
    // tvec[j] = sum_i sign_i X[i][j] (rows of bufB); uvec[i] = sum_j X[i][j] sign_j (rows of bufA)
    const int o = tid >> 1, h = tid & 1;  // o: output 0..127, h: half
    const short* src = (o < 64) ? &bufB[o * LSH + 32 * h]
                                : &bufA[(o - 64) * LSH + 32 * h];
    float acc = 0.0f;
#pragma unroll
    for (int p = 0; p < 4; ++p) {
      const short8 v = ldrow(src + 8 * p);
#pragma unroll
      for (int j = 0; j < 8; ++j) {
        const float f = bf2f(v[j]);
        acc += (j & 1) ? -f : f;  // element index 32h+8p+j, parity = j&1
      }
    }
    acc += __shfl_xor(acc, 1);
    if (h == 0) {
      if (o < 64) tvec[o] = acc; else uvec[o - 64] = acc;
    }
  }
  __syncthreads();  // B2: tvec/uvec published

  // ---- Phase C: MFMA Rt, Lt (frags from ftab t=1) + M2 sRv/Luv + sigv ----
  f32x16 Rt, Lt;
#pragma unroll
  for (int r = 0; r < 16; ++r) { Rt[r] = 0.0f; Lt[r] = 0.0f; }
#pragma unroll
  for (int kk = 0; kk < 4; ++kk) {
    const short8 aR = *(const short8*)&ftab[((rb * 4 + kk) * 64 + lane) * 8];  // (gr,rb)
    const short8 bR = ldrow(&bufA[(cb * 32 + l31) * LSH + kk * 16 + q * 8]);
    Rt = __builtin_amdgcn_mfma_f32_32x32x16_bf16(aR, bR, Rt, 0, 0, 0);
    const short8 aL = ldrow(&bufB[(rb * 32 + l31) * LSH + kk * 16 + q * 8]);
    const short8 bL = *(const short8*)&ftab[((cb * 4 + kk) * 64 + lane) * 8];  // (gr,cb)
    Lt = __builtin_amdgcn_mfma_f32_32x32x16_bf16(aL, bL, Lt, 0, 0, 0);
  }
  {
    // sRv[j] = sum_m tvec[m]*g64[(j-m)&63] ; Luv[i] = sum_m g64[(i-m)&63]*uvec[m]
    const int o = tid >> 1, h = tid & 1;
    const int o63 = o & 63;
    const float* vsrc = (o < 64) ? tvec : uvec;  // wave-uniform select
    float acc = 0.0f;
#pragma unroll
    for (int p = 0; p < 32; ++p) {
      const int m = 32 * h + p;
      acc += vsrc[m] * g64[(o63 - m) & 63];
    }
    acc += __shfl_xor(acc, 1);
    if (h == 0) {
      if (o < 64) sRv[o] = acc; else Luv[o - 64] = acc;
    }
  }
  if (w == 0) {  // sigv = s^T X s = sum_j sign_j * tvec[j]
    float sv = (lane & 1) ? -tvec[lane] : tvec[lane];
#pragma unroll
    for (int d_ = 1; d_ < 64; d_ <<= 1) sv += __shfl_xor(sv, d_);
    if (lane == 0) sigv = sv;
  }
  __syncthreads();  // B3

  // ---- P2: issue ftab t=0 loads; z_eoT -> bufA, Lt -> bufB (packed) ----
  f32x4 u0, u1;
  {
    const f32x4* fsrc = (const f32x4*)g_ftw;  // t=0 half
    u0 = fsrc[tid];
    u1 = fsrc[tid + 256];
  }
  float zoe[16];
  {
    const int icol = cb * 32 + l31;
    const float sgi = (icol & 1) ? -1.0f : 1.0f;
#pragma unroll
    for (int k = 0; k < 4; ++k) {
      const int jb = rb * 32 + 4 * q + 8 * k;  // jrow = jb + t, t=0..3
      short ze[4], zl[4];
#pragma unroll
      for (int t = 0; t < 4; ++t) {
        const int r = 4 * k + t;
        const int jrow = jb + t;
        const float sgj = (jrow & 1) ? -1.0f : 1.0f;
        const float veo = Rt[r] + sgi * sRv[jrow] * (1.0f / 64.0f);
        ze[t] = f2bf(veo * veo);               // z_eo[i][j]
        zl[t] = f2bf(Lt[r]);                   // L[i][j]
        const float voe = Lt[r] + Luv[icol] * sgj * (1.0f / 64.0f);
        zoe[r] = voe * voe;                    // z_oeT[j][i] (C-layout)
      }
      uint2 pz, pl;
      pz.x = pk2(ze[0], ze[1]); pz.y = pk2(ze[2], ze[3]);
      pl.x = pk2(zl[0], zl[1]); pl.y = pk2(zl[2], zl[3]);
      *(uint2*)&bufA[icol * LSH + jb] = pz;
      *(uint2*)&bufB[icol * LSH + jb] = pl;
    }
  }
  __syncthreads();  // B4

  // ---- P3: OOt = M*Lt (ftab t=1, bufB=L) ; z_oo -> bufC (packed) ----
  f32x16 OOt;
#pragma unroll
  for (int r = 0; r < 16; ++r) OOt[r] = 0.0f;
#pragma unroll
  for (int kk = 0; kk < 4; ++kk) {
    const short8 a = *(const short8*)&ftab[((rb * 4 + kk) * 64 + lane) * 8];  // (gr,rb)
    const short8 b = ldrow(&bufB[(cb * 32 + l31) * LSH + kk * 16 + q * 8]);
    OOt = __builtin_amdgcn_mfma_f32_32x32x16_bf16(a, b, OOt, 0, 0, 0);
  }
  {
    const int icol = cb * 32 + l31;
#pragma unroll
    for (int k = 0; k < 4; ++k) {
      const int jb = rb * 32 + 4 * q + 8 * k;
      short zo[4];
#pragma unroll
      for (int t = 0; t < 4; ++t) {
        const int r = 4 * k + t;
        zo[t] = f2bf(OOt[r] * OOt[r]);
      }
      uint2 p;
      p.x = pk2(zo[0], zo[1]); p.y = pk2(zo[2], zo[3]);
      *(uint2*)&bufC[icol * LSH + jb] = p;  // z_oo[i][j]
    }
  }
  // pin: t=0 staging values must be materialized by here (P2+P3 covered the
  // L2 latency); only 8 VGPRs, short lifetime -> no spill pressure.
  asm volatile("" : "+v"(u0), "+v"(u1));
  __syncthreads();  // B5: all ftab t=1 reads done

  // ---- swap ftab to t=0 half ----
  {
    f32x4* fdst = (f32x4*)ftab;
    fdst[tid] = u0;
    fdst[tid + 256] = u1;
  }
  __syncthreads();  // B5b: ftab(t=0) published

  // ---- P4: Ut = z_oeT + M^T z_ooT ; W = z_eo*M ; U^T -> bufB ----
  f32x16 Ut, Wv;
#pragma unroll
  for (int r = 0; r < 16; ++r) { Ut[r] = zoe[r]; Wv[r] = 0.0f; }
#pragma unroll
  for (int kk = 0; kk < 4; ++kk) {
    const short8 aU = *(const short8*)&ftab[((rb * 4 + kk) * 64 + lane) * 8];  // (g,rb)
    const short8 bU = ldrow(&bufC[(cb * 32 + l31) * LSH + kk * 16 + q * 8]);
    Ut = __builtin_amdgcn_mfma_f32_32x32x16_bf16(aU, bU, Ut, 0, 0, 0);
    const short8 aW = ldrow(&bufA[(rb * 32 + l31) * LSH + kk * 16 + q * 8]);  // z_eo rows
    const short8 bW = *(const short8*)&ftab[((cb * 4 + kk) * 64 + lane) * 8];  // (g,cb)
    Wv = __builtin_amdgcn_mfma_f32_32x32x16_bf16(aW, bW, Wv, 0, 0, 0);
  }
#pragma unroll
  for (int r = 0; r < 16; ++r) {
    const int jrow = rb * 32 + (r & 3) + 4 * q + 8 * (r >> 2);
    const int icol = cb * 32 + l31;
    bufB[jrow * LSH + icol] = f2bf(Ut[r]);  // U^T row-major (rows=j); strided, scalar
  }
  __syncthreads();  // B6

  // ---- P5: V = M^T U ; epilogue (x from regs; no global re-read) ----
  f32x16 Vv;
#pragma unroll
  for (int r = 0; r < 16; ++r) Vv[r] = 0.0f;
#pragma unroll
  for (int kk = 0; kk < 4; ++kk) {
    const short8 a = *(const short8*)&ftab[((rb * 4 + kk) * 64 + lane) * 8];  // (g,rb)
    const short8 b = ldrow(&bufB[(cb * 32 + l31) * LSH + kk * 16 + q * 8]);
    Vv = __builtin_amdgcn_mfma_f32_32x32x16_bf16(a, b, Vv, 0, 0, 0);
  }

  const float c0 = coef[0], c1 = coef[1];
  const float c2q = 0.25f * coef[2];
  float* ob = out + base;
#pragma unroll
  for (int r = 0; r < 16; ++r) {
    const int irow = rb * 32 + (r & 3) + 4 * q + 8 * (r >> 2);
    const float sgi = (irow & 1) ? -1.0f : 1.0f;
    const float sgj = (jcol & 1) ? -1.0f : 1.0f;
    const float xv_ = bf2f(f2bf(xcur[r]));  // bit-identical to Xr round-trip
    const float vee = xv_ + (sgi * tvec[jcol] + uvec[irow] * sgj) * (1.0f / 64.0f) +
                      sgi * sgj * sigv * (1.0f / 4096.0f);
    const float zee = vee * vee;
    ob[irow * 64 + jcol] = c0 + c1 * xcur[r] + c2q * (zee + Vv[r] + Wv[r]);
  }
}

extern "C" void kernel_launch(void* const* d_in, const int* in_sizes, int n_in,
                              void* d_out, int out_size, void* d_ws,
                              size_t ws_size, hipStream_t stream) {
  const float* x = (const float*)d_in[0];
  const float* coef = (const float*)d_in[1];
  float* out = (float*)d_out;
  const int channels = out_size / 4096;  // 32*128 channels of 64x64
  uppolyact_setup<<<dim3(1), dim3(256), 0, stream>>>();
  uppolyact_kernel<<<dim3(channels), dim3(256), 0, stream>>>(x, coef, out);
}